// Round 1
// baseline (8563.081 us; speedup 1.0000x reference)
//
#include <hip/hip_runtime.h>
#include <hip/hip_bf16.h>

#define BTOT 2048
#define VV 32000
#define HH 1024
#define INNER 2048
#define NA 17

__device__ __forceinline__ bool vi_better(float va, int ia, float vb, int ib) {
    // jax.lax.top_k order: larger value first; ties -> smaller index first
    return (va > vb) || (va == vb && ia < ib);
}

// ---------------------------------------------------------------------------
// Kernel 1: per-row top-16 (+dedup vs label), log-softmax stats, lp gather
// ---------------------------------------------------------------------------
__global__ __launch_bounds__(256)
void topk_lse_kernel(const float* __restrict__ logits,
                     const int* __restrict__ labels,
                     const unsigned char* __restrict__ future_valid,
                     int* __restrict__ actions,
                     int* __restrict__ amask,
                     float* __restrict__ lp,
                     int* __restrict__ rvalid,
                     int* __restrict__ validcount)
{
    const int r = blockIdx.x;
    const int t = threadIdx.x;
    const float* __restrict__ lrow = logits + (size_t)r * VV;

    __shared__ float cv[4096];
    __shared__ int   ci[4096];
    __shared__ float rvv[256];
    __shared__ int   rii[256];
    __shared__ float s_topv[16];
    __shared__ int   s_topi[16];
    __shared__ float s_red[256];

    // thread-local top-16 (sorted desc), fully unrolled predicated insert so it
    // stays in VGPRs
    float lv[16]; int li[16];
#pragma unroll
    for (int k = 0; k < 16; ++k) { lv[k] = -INFINITY; li[k] = 0x7fffffff; }

    for (int idx = t; idx < VV; idx += 256) {
        float x = lrow[idx];
        if (vi_better(x, idx, lv[15], li[15])) {
#pragma unroll
            for (int k = 15; k >= 1; --k) {
                bool bk  = vi_better(x, idx, lv[k],   li[k]);
                bool bk1 = vi_better(x, idx, lv[k-1], li[k-1]);
                if (bk) {
                    if (bk1) { lv[k] = lv[k-1]; li[k] = li[k-1]; }
                    else     { lv[k] = x;       li[k] = idx;     }
                }
            }
            if (vi_better(x, idx, lv[0], li[0])) { lv[0] = x; li[0] = idx; }
        }
    }
#pragma unroll
    for (int k = 0; k < 16; ++k) { cv[t*16+k] = lv[k]; ci[t*16+k] = li[k]; }
    __syncthreads();

    // 16 rounds of global argmax over the 4096 candidates
    for (int round = 0; round < 16; ++round) {
        float bv = -INFINITY; int bi = 0x7fffffff; int bslot = -1;
#pragma unroll
        for (int k = 0; k < 16; ++k) {
            float v = cv[t*16+k]; int i2 = ci[t*16+k];
            if (vi_better(v, i2, bv, bi)) { bv = v; bi = i2; bslot = t*16+k; }
        }
        rvv[t] = bv; rii[t] = bi;
        __syncthreads();
        for (int s = 128; s > 0; s >>= 1) {
            if (t < s) {
                if (vi_better(rvv[t+s], rii[t+s], rvv[t], rii[t])) {
                    rvv[t] = rvv[t+s]; rii[t] = rii[t+s];
                }
            }
            __syncthreads();
        }
        float gv2 = rvv[0]; int gi2 = rii[0];
        if (t == 0) { s_topv[round] = gv2; s_topi[round] = gi2; }
        if (bslot >= 0 && bv == gv2 && bi == gi2) {
            cv[bslot] = -INFINITY; ci[bslot] = 0x7fffffff;  // remove winner
        }
        __syncthreads();
    }

    // log-sum-exp with max = top value
    float m = s_topv[0];
    float se = 0.f;
    for (int idx = t; idx < VV; idx += 256) se += expf(lrow[idx] - m);
    s_red[t] = se;
    __syncthreads();
    for (int s = 128; s > 0; s >>= 1) {
        if (t < s) s_red[t] += s_red[t+s];
        __syncthreads();
    }
    float lse = m + logf(s_red[0]);

    int lbl = labels[r];
    if (t < 16) {
        int ai = s_topi[t];
        actions[r*NA + t] = ai;
        amask[r*NA + t]   = 1;
        lp[r*NA + t]      = lrow[ai] - lse;
    } else if (t == 16) {
        bool dup = false;
#pragma unroll
        for (int k = 0; k < 16; ++k) dup = dup || (s_topi[k] == lbl);
        actions[r*NA + 16] = dup ? 0 : lbl;
        amask[r*NA + 16]   = dup ? 0 : 1;
        lp[r*NA + 16]      = dup ? 0.f : (lrow[lbl] - lse);
        bool valid = (lbl != -100) && (future_valid[r] != 0);
        rvalid[r] = valid ? 1 : 0;
        if (valid) atomicAdd(validcount, 1);
    }
}

// ---------------------------------------------------------------------------
// Kernel 2: per-row MLP (17 actions fused), LayerNorm, cosine, softmax, loss
// ---------------------------------------------------------------------------
__device__ __forceinline__ float block_sum(float v, float* tmp4, int t) {
#pragma unroll
    for (int off = 32; off > 0; off >>= 1) v += __shfl_down(v, off, 64);
    if ((t & 63) == 0) tmp4[t >> 6] = v;
    __syncthreads();
    float r = tmp4[0] + tmp4[1] + tmp4[2] + tmp4[3];
    __syncthreads();
    return r;
}

__global__ __launch_bounds__(256)
void mlp_score_kernel(const float* __restrict__ hidden,
                      const float* __restrict__ future,
                      const float* __restrict__ embed,
                      const float* __restrict__ W1,
                      const float* __restrict__ b1,
                      const float* __restrict__ W2,
                      const float* __restrict__ b2,
                      const float* __restrict__ ln_g,
                      const float* __restrict__ ln_b,
                      const int* __restrict__ actions,
                      const int* __restrict__ amask,
                      const float* __restrict__ lp,
                      const int* __restrict__ rvalid,
                      const int* __restrict__ validcount,
                      float* __restrict__ out)
{
    const int r = blockIdx.x;
    const int t = threadIdx.x;

    __shared__ float s_hidden[HH];               // 4 KB (kept f32: shared part)
    __shared__ float s_future[HH];               // 4 KB
    __shared__ __hip_bfloat16 s_emb[NA][HH];     // 34 KB
    __shared__ __hip_bfloat16 s_hblk[NA][512];   // 17 KB (GELU output block)
    __shared__ float s_tmp4[4];
    __shared__ float s_scores[NA];

    for (int j = t; j < HH; j += 256) {
        s_hidden[j] = hidden[(size_t)r*HH + j];
        s_future[j] = future[(size_t)r*HH + j];
    }
#pragma unroll
    for (int a = 0; a < NA; ++a) {
        int id = actions[r*NA + a];
        const float* erow = embed + (size_t)id * HH;
        for (int j = t; j < HH; j += 256)
            s_emb[a][j] = __float2bfloat16(erow[j]);
    }
    __syncthreads();

    // delta accumulators: thread t owns j = t + 256*kk for each action
    float dacc[NA][4];
#pragma unroll
    for (int a = 0; a < NA; ++a)
#pragma unroll
        for (int kk = 0; kk < 4; ++kk) dacc[a][kk] = 0.f;

    for (int blk = 0; blk < INNER; blk += 512) {
        const int i0 = blk + t;
        const int i1 = blk + t + 256;

        // layer-1 hidden half: shared across all 17 actions (computed once)
        float hacc0 = 0.f, hacc1 = 0.f;
        for (int f = 0; f < HH; ++f) {
            float w0 = W1[(size_t)f * INNER + i0];
            float w1 = W1[(size_t)f * INNER + i1];
            float x = s_hidden[f];
            hacc0 = fmaf(x, w0, hacc0);
            hacc1 = fmaf(x, w1, hacc1);
        }
        // layer-1 embed half, per action
        float eacc[NA][2];
#pragma unroll
        for (int a = 0; a < NA; ++a) { eacc[a][0] = 0.f; eacc[a][1] = 0.f; }
        for (int f = 0; f < HH; ++f) {
            float w0 = W1[(size_t)(HH + f) * INNER + i0];
            float w1 = W1[(size_t)(HH + f) * INNER + i1];
#pragma unroll
            for (int a = 0; a < NA; ++a) {
                float x = __bfloat162float(s_emb[a][f]);
                eacc[a][0] = fmaf(x, w0, eacc[a][0]);
                eacc[a][1] = fmaf(x, w1, eacc[a][1]);
            }
        }
        float bb0 = b1[i0], bb1 = b1[i1];
#pragma unroll
        for (int a = 0; a < NA; ++a) {
            float p0 = hacc0 + eacc[a][0] + bb0;
            float p1 = hacc1 + eacc[a][1] + bb1;
            // exact GELU (approximate=False): 0.5*x*(1+erf(x/sqrt(2)))
            float h0 = 0.5f * p0 * (1.f + erff(p0 * 0.70710678118654752f));
            float h1 = 0.5f * p1 * (1.f + erff(p1 * 0.70710678118654752f));
            s_hblk[a][t]       = __float2bfloat16(h0);
            s_hblk[a][t + 256] = __float2bfloat16(h1);
        }
        __syncthreads();

        // layer 2: delta[a][j] += h[a][i] * W2[i][j] over this i-block
        for (int ii = 0; ii < 512; ++ii) {
            int i = blk + ii;
            float w[4];
#pragma unroll
            for (int kk = 0; kk < 4; ++kk)
                w[kk] = W2[(size_t)i * HH + t + 256*kk];
#pragma unroll
            for (int a = 0; a < NA; ++a) {
                float hv = __bfloat162float(s_hblk[a][ii]);
#pragma unroll
                for (int kk = 0; kk < 4; ++kk)
                    dacc[a][kk] = fmaf(hv, w[kk], dacc[a][kk]);
            }
        }
        __syncthreads();
    }

    // epilogue: +b2, LayerNorm, cosine vs normalized future
    float b2v[4], gv[4], bbv[4], fv[4];
#pragma unroll
    for (int kk = 0; kk < 4; ++kk) {
        int j = t + 256*kk;
        b2v[kk] = b2[j]; gv[kk] = ln_g[j]; bbv[kk] = ln_b[j]; fv[kk] = s_future[j];
    }
    float sf2p = 0.f;
#pragma unroll
    for (int kk = 0; kk < 4; ++kk) sf2p += fv[kk]*fv[kk];
    float Sf2 = block_sum(sf2p, s_tmp4, t);
    float fnorm = fmaxf(sqrtf(Sf2), 1e-12f);

#pragma unroll
    for (int a = 0; a < NA; ++a) {
        float d[4];
        float s1p = 0.f, s2p = 0.f;
#pragma unroll
        for (int kk = 0; kk < 4; ++kk) {
            d[kk] = dacc[a][kk] + b2v[kk];
            s1p += d[kk]; s2p += d[kk]*d[kk];
        }
        float S1 = block_sum(s1p, s_tmp4, t);
        float S2 = block_sum(s2p, s_tmp4, t);
        float mu = S1 * (1.f/(float)HH);
        float var = S2 * (1.f/(float)HH) - mu*mu;
        float rstd = rsqrtf(var + 1e-5f);
        float sar2p = 0.f, safp = 0.f;
#pragma unroll
        for (int kk = 0; kk < 4; ++kk) {
            float ar = (d[kk]-mu)*rstd*gv[kk] + bbv[kk];
            sar2p += ar*ar; safp += ar*fv[kk];
        }
        float Sar2 = block_sum(sar2p, s_tmp4, t);
        float Saf  = block_sum(safp,  s_tmp4, t);
        if (t == 0) {
            float anorm = fmaxf(sqrtf(Sar2), 1e-12f);
            float sc = Saf / (anorm * fnorm);
            s_scores[a] = amask[r*NA+a] ? sc : -1e9f;  // mask BEFORE softmax
        }
    }
    __syncthreads();

    if (t == 0) {
        int validr = rvalid[r];
        float mx = -INFINITY;
#pragma unroll
        for (int a = 0; a < NA; ++a) mx = fmaxf(mx, s_scores[a]);
        float ex[NA]; float sesum = 0.f;
#pragma unroll
        for (int a = 0; a < NA; ++a) { ex[a] = expf(s_scores[a] - mx); sesum += ex[a]; }
        float acc = 0.f; int denom = 0;
#pragma unroll
        for (int a = 0; a < NA; ++a) {
            int mk = amask[r*NA+a];
            int mv = (mk && validr) ? 1 : 0;
            float rw = (ex[a]/sesum) * (float)mk;   // rewards = softmax * mask
            acc += rw * lp[r*NA+a] * (float)mv;     // lp_actions masked by mask&valid
            denom += mv;
        }
        float lossr = -acc / (float)(denom > 0 ? denom : 1) * (float)validr;
        float normz = fmaxf((float)(*validcount), 1.f);
        atomicAdd(out, lossr / normz);
    }
}

// ---------------------------------------------------------------------------
extern "C" void kernel_launch(void* const* d_in, const int* in_sizes, int n_in,
                              void* d_out, int out_size, void* d_ws, size_t ws_size,
                              hipStream_t stream)
{
    const float* logits        = (const float*)d_in[0];
    const float* hidden        = (const float*)d_in[1];
    const int*   labels        = (const int*)d_in[2];
    const float* future        = (const float*)d_in[3];
    const unsigned char* fvld  = (const unsigned char*)d_in[4];  // jnp.bool_ = 1 byte
    const float* embed         = (const float*)d_in[5];
    const float* W1            = (const float*)d_in[6];
    const float* b1            = (const float*)d_in[7];
    const float* W2            = (const float*)d_in[8];
    const float* b2            = (const float*)d_in[9];
    const float* ln_g          = (const float*)d_in[10];
    const float* ln_b          = (const float*)d_in[11];
    float* out = (float*)d_out;

    // workspace layout (~426 KB)
    char* ws = (char*)d_ws;
    int*   validcount = (int*)ws;                          // 16 B reserved
    int*   actions    = (int*)(ws + 16);                   // BTOT*NA i32
    int*   amask      = (int*)(ws + 16 + 1*BTOT*NA*4);
    float* lp         = (float*)(ws + 16 + 2*BTOT*NA*4);
    int*   rvalid     = (int*)(ws + 16 + 3*BTOT*NA*4);

    (void)hipMemsetAsync(d_out, 0, sizeof(float), stream);
    (void)hipMemsetAsync(d_ws, 0, 16, stream);

    topk_lse_kernel<<<BTOT, 256, 0, stream>>>(logits, labels, fvld,
                                              actions, amask, lp, rvalid, validcount);
    mlp_score_kernel<<<BTOT, 256, 0, stream>>>(hidden, future, embed, W1, b1, W2, b2,
                                               ln_g, ln_b, actions, amask, lp,
                                               rvalid, validcount, out);
}

// Round 2
// 8389.680 us; speedup vs baseline: 1.0207x; 1.0207x over previous
//
#include <hip/hip_runtime.h>
#include <hip/hip_bf16.h>
#include <math.h>

#define BTOT 2048
#define VV 32000
#define HH 1024
#define INNER 2048
#define NA 17

typedef __bf16 bf16;
typedef __bf16 bf16x8 __attribute__((ext_vector_type(8)));
typedef float f32x4 __attribute__((ext_vector_type(4)));

__device__ __forceinline__ f32x4 mfma16(bf16x8 a, bf16x8 b, f32x4 c) {
    return __builtin_amdgcn_mfma_f32_16x16x32_bf16(a, b, c, 0, 0, 0);
}

__device__ __forceinline__ bool vi_better(float va, int ia, float vb, int ib) {
    // jax.lax.top_k order: larger value first; ties -> smaller index first
    return (va > vb) || (va == vb && ia < ib);
}

// ---------------------------------------------------------------------------
// Kernel 0: tiled transpose f32 -> bf16.  dst[c][r] = (bf16)src[r][c]
// src is R x C row-major; dst is C x R row-major. R, C multiples of 32.
// ---------------------------------------------------------------------------
__global__ __launch_bounds__(256)
void transpose_to_bf16(const float* __restrict__ src, bf16* __restrict__ dst,
                       int R, int C)
{
    __shared__ float tile[32][33];
    const int bx = blockIdx.x * 32;   // column block of src
    const int by = blockIdx.y * 32;   // row block of src
    const int tx = threadIdx.x;       // 0..31
    const int ty = threadIdx.y;       // 0..7
#pragma unroll
    for (int i = 0; i < 32; i += 8)
        tile[ty + i][tx] = src[(size_t)(by + ty + i) * C + bx + tx];
    __syncthreads();
#pragma unroll
    for (int i = 0; i < 32; i += 8)
        dst[(size_t)(bx + ty + i) * R + by + tx] = (bf16)tile[tx][ty + i];
}

// ---------------------------------------------------------------------------
// Kernel 1: per-row top-16 + fused online log-sum-exp (single logits read)
// ---------------------------------------------------------------------------
__global__ __launch_bounds__(256)
void topk_lse_kernel(const float* __restrict__ logits,
                     const int* __restrict__ labels,
                     const unsigned char* __restrict__ future_valid,
                     int* __restrict__ actions,
                     int* __restrict__ amask,
                     float* __restrict__ lp,
                     int* __restrict__ rvalid,
                     int* __restrict__ validcount)
{
    const int r = blockIdx.x;
    const int t = threadIdx.x;
    const float* __restrict__ lrow = logits + (size_t)r * VV;

    __shared__ float cv[4096];
    __shared__ int   ci[4096];
    __shared__ float candv[256];
    __shared__ int   candi[256];
    __shared__ float s_topv[16];
    __shared__ int   s_topi[16];
    __shared__ int   s_wtid;
    __shared__ float s_red[256];

    float lv[16]; int li[16];
#pragma unroll
    for (int k = 0; k < 16; ++k) { lv[k] = -INFINITY; li[k] = 0x7fffffff; }
    float mrun = -INFINITY, srun = 0.f;

    const float4* __restrict__ lrow4 = (const float4*)lrow;
    for (int i = 0; i < 32; ++i) {
        int i4 = t + 256 * i;
        if (i4 < VV / 4) {
            float4 xv = lrow4[i4];
            float xs[4] = {xv.x, xv.y, xv.z, xv.w};
#pragma unroll
            for (int cc = 0; cc < 4; ++cc) {
                float x = xs[cc];
                int idx = i4 * 4 + cc;
                // online log-sum-exp
                if (x > mrun) { srun = srun * __expf(mrun - x) + 1.f; mrun = x; }
                else          { srun += __expf(x - mrun); }
                // top-16 sorted insert (registers only)
                if (vi_better(x, idx, lv[15], li[15])) {
#pragma unroll
                    for (int k = 15; k >= 1; --k) {
                        bool bk  = vi_better(x, idx, lv[k],   li[k]);
                        bool bk1 = vi_better(x, idx, lv[k-1], li[k-1]);
                        if (bk) {
                            if (bk1) { lv[k] = lv[k-1]; li[k] = li[k-1]; }
                            else     { lv[k] = x;       li[k] = idx;     }
                        }
                    }
                    if (vi_better(x, idx, lv[0], li[0])) { lv[0] = x; li[0] = idx; }
                }
            }
        }
    }
#pragma unroll
    for (int k = 0; k < 16; ++k) { cv[t*16+k] = lv[k]; ci[t*16+k] = li[k]; }
    candv[t] = lv[0]; candi[t] = li[0];
    __syncthreads();

    // 16 extraction rounds: wave0 shuffle-argmax over 256 list heads,
    // only the winning thread advances its cursor.
    int cur = 0;
    for (int round = 0; round < 16; ++round) {
        if (t < 64) {
            float bv = -INFINITY; int bi = 0x7fffffff; int btid = -1;
#pragma unroll
            for (int k2 = 0; k2 < 4; ++k2) {
                int tid = t + 64 * k2;
                float v = candv[tid]; int ii = candi[tid];
                if (vi_better(v, ii, bv, bi)) { bv = v; bi = ii; btid = tid; }
            }
#pragma unroll
            for (int m2 = 1; m2 < 64; m2 <<= 1) {
                float ov = __shfl_xor(bv, m2, 64);
                int   oi = __shfl_xor(bi, m2, 64);
                int   ot = __shfl_xor(btid, m2, 64);
                if (vi_better(ov, oi, bv, bi)) { bv = ov; bi = oi; btid = ot; }
            }
            if (t == 0) { s_topv[round] = bv; s_topi[round] = bi; s_wtid = btid; }
        }
        __syncthreads();
        if (t == s_wtid) {
            ++cur;
            candv[t] = (cur < 16) ? cv[t*16+cur] : -INFINITY;
            candi[t] = (cur < 16) ? ci[t*16+cur] : 0x7fffffff;
        }
        __syncthreads();
    }

    // combine per-thread online (m,s) into global LSE; M = global max = top-1
    float M = s_topv[0];
    s_red[t] = (mrun > -INFINITY) ? srun * __expf(mrun - M) : 0.f;
    __syncthreads();
    for (int s = 128; s > 0; s >>= 1) {
        if (t < s) s_red[t] += s_red[t+s];
        __syncthreads();
    }
    float lse = M + logf(s_red[0]);

    int lbl = labels[r];
    if (t < 16) {
        int ai = s_topi[t];
        actions[r*NA + t] = ai;
        amask[r*NA + t]   = 1;
        lp[r*NA + t]      = lrow[ai] - lse;
    } else if (t == 16) {
        bool dup = false;
#pragma unroll
        for (int k = 0; k < 16; ++k) dup = dup || (s_topi[k] == lbl);
        actions[r*NA + 16] = dup ? 0 : lbl;
        amask[r*NA + 16]   = dup ? 0 : 1;
        lp[r*NA + 16]      = dup ? 0.f : (lrow[lbl] - lse);
        bool valid = (lbl != -100) && (future_valid[r] != 0);
        rvalid[r] = valid ? 1 : 0;
        if (valid) atomicAdd(validcount, 1);
    }
}

// ---------------------------------------------------------------------------
// Kernel 2: per-row fused MLP via MFMA.
// A (32x2048, 17 real rows) = [hidden | embed_a]; L1 -> GELU -> L2 -> LN ->
// cosine -> softmax -> loss.  W1T/W2T are pre-transposed bf16 (N-major).
// Layouts (verified m89/m91/m120): A[m=lane&15][k=(lane>>4)*8+j],
// B[k=(lane>>4)*8+j][n=lane&15], C/D: col=lane&15, row=(lane>>4)*4+reg.
// ---------------------------------------------------------------------------
#define FP 1032   // s_fused row pitch (1024+8) -> bank-conflict-free-ish
#define YP 264    // s_y row pitch (256+8)

__global__ __launch_bounds__(256, 2)
void mlp_mfma_kernel(const float* __restrict__ hidden,
                     const float* __restrict__ future,
                     const float* __restrict__ embed,
                     const bf16* __restrict__ W1T,   // [2048][2048]
                     const float* __restrict__ b1,
                     const bf16* __restrict__ W2T,   // [1024][2048]
                     const float* __restrict__ b2,
                     const float* __restrict__ ln_g,
                     const float* __restrict__ ln_b,
                     const int* __restrict__ actions,
                     const int* __restrict__ amask,
                     const float* __restrict__ lp,
                     const int* __restrict__ rvalid,
                     const int* __restrict__ validcount,
                     float* __restrict__ out)
{
    const int r = blockIdx.x;
    const int t = threadIdx.x;
    const int w = t >> 6;        // wave 0..3
    const int lane = t & 63;
    const int q = lane >> 4;     // quad
    const int c = lane & 15;

    __shared__ bf16  s_fused[18 * FP];   // row 0: hidden; rows 1..17: embeds
    __shared__ bf16  s_y[32 * YP];       // GELU output chunk (32 x 256)
    __shared__ float s_future[HH];
    __shared__ float s_p1[32][4], s_p2[32][4];
    __shared__ float s_mu[32], s_rstd[32];
    __shared__ float s_pa[32][4], s_pf[32][4];
    __shared__ float s_scores[NA];
    __shared__ float s_tmp[4];

    for (int j = t; j < HH; j += 256) {
        s_fused[j] = (bf16)hidden[(size_t)r*HH + j];
        s_future[j] = future[(size_t)r*HH + j];
    }
#pragma unroll 1
    for (int a = 0; a < NA; ++a) {
        const float* erow = embed + (size_t)actions[r*NA + a] * HH;
        for (int j = t; j < HH; j += 256)
            s_fused[(1+a)*FP + j] = (bf16)erow[j];
    }
    __syncthreads();

    // future norm (block reduce)
    float pf2 = 0.f;
    for (int j = t; j < HH; j += 256) { float v = s_future[j]; pf2 += v*v; }
#pragma unroll
    for (int m2 = 1; m2 < 64; m2 <<= 1) pf2 += __shfl_xor(pf2, m2, 64);
    if (lane == 0) s_tmp[w] = pf2;
    __syncthreads();
    const float fnorm = fmaxf(sqrtf(s_tmp[0]+s_tmp[1]+s_tmp[2]+s_tmp[3]), 1e-12f);

    const f32x4 zero4 = {0.f, 0.f, 0.f, 0.f};
    f32x4 accB[2][16];
#pragma unroll
    for (int mt = 0; mt < 2; ++mt)
#pragma unroll
        for (int nt = 0; nt < 16; ++nt) accB[mt][nt] = zero4;

    const int er0 = 1 + c;   // embed row for A-tile0 row m=c
    const int er1 = 17;      // A-tile1: row 16 real (action 16), rest clamped

    for (int ci = 0; ci < 8; ++ci) {
        // ---- phase A: P = A @ W1[:, chunk]  (per wave: 64 cols) ----
        f32x4 accA[2][4];
#pragma unroll
        for (int mt = 0; mt < 2; ++mt)
#pragma unroll
            for (int nt = 0; nt < 4; ++nt) accA[mt][nt] = zero4;

        const int nw0 = ci*256 + w*64;
        for (int ks = 0; ks < 64; ++ks) {
            const int k = ks*32 + q*8;
            bf16x8 a0, a1;
            if (ks < 32) {                       // k < 1024: hidden (all rows)
                a0 = *(const bf16x8*)&s_fused[k];
                a1 = a0;
            } else {                             // k >= 1024: per-action embed
                const int col = k - 1024;
                a0 = *(const bf16x8*)&s_fused[er0*FP + col];
                a1 = *(const bf16x8*)&s_fused[er1*FP + col];
            }
#pragma unroll
            for (int nt = 0; nt < 4; ++nt) {
                const int n = nw0 + nt*16 + c;
                bf16x8 bf = *(const bf16x8*)&W1T[(size_t)n*INNER + k];
                accA[0][nt] = mfma16(a0, bf, accA[0][nt]);
                accA[1][nt] = mfma16(a1, bf, accA[1][nt]);
            }
        }

        __syncthreads();   // prev chunk's phase-B s_y reads complete
        // ---- bias + GELU -> s_y (bf16) ----
#pragma unroll
        for (int mt = 0; mt < 2; ++mt)
#pragma unroll
            for (int nt = 0; nt < 4; ++nt) {
                const int jcol = w*64 + nt*16 + c;
                const float bb = b1[ci*256 + jcol];
                f32x4 v = accA[mt][nt];
#pragma unroll
                for (int reg = 0; reg < 4; ++reg) {
                    const int m = mt*16 + q*4 + reg;
                    const float x = v[reg] + bb;
                    const float g = 0.5f * x * (1.f + erff(x * 0.70710678118654752f));
                    s_y[m*YP + jcol] = (bf16)g;
                }
            }
        __syncthreads();   // s_y ready

        // ---- phase B: delta += Y_chunk @ W2[chunk, :]  (per wave: 256 js) ----
        for (int ks = 0; ks < 8; ++ks) {
            const int kk = ks*32 + q*8;
            bf16x8 a0 = *(const bf16x8*)&s_y[c*YP + kk];
            bf16x8 a1 = *(const bf16x8*)&s_y[(16+c)*YP + kk];
            const int ig = ci*256 + kk;
#pragma unroll 4
            for (int nt = 0; nt < 16; ++nt) {
                const int j = w*256 + nt*16 + c;
                bf16x8 bf = *(const bf16x8*)&W2T[(size_t)j*INNER + ig];
                accB[0][nt] = mfma16(a0, bf, accB[0][nt]);
                accB[1][nt] = mfma16(a1, bf, accB[1][nt]);
            }
        }
    }

    // ---- epilogue: +b2, LayerNorm stats, cosine, softmax, loss ----
    float p1[2][4], p2[2][4];
#pragma unroll
    for (int mt = 0; mt < 2; ++mt)
#pragma unroll
        for (int reg = 0; reg < 4; ++reg) { p1[mt][reg] = 0.f; p2[mt][reg] = 0.f; }
#pragma unroll
    for (int mt = 0; mt < 2; ++mt)
#pragma unroll 4
        for (int nt = 0; nt < 16; ++nt) {
            const int j = w*256 + nt*16 + c;
            const float bb2 = b2[j];
#pragma unroll
            for (int reg = 0; reg < 4; ++reg) {
                const float d = accB[mt][nt][reg] + bb2;
                p1[mt][reg] += d; p2[mt][reg] += d*d;
            }
        }
#pragma unroll
    for (int m2 = 1; m2 <= 8; m2 <<= 1)
#pragma unroll
        for (int mt = 0; mt < 2; ++mt)
#pragma unroll
            for (int reg = 0; reg < 4; ++reg) {
                p1[mt][reg] += __shfl_xor(p1[mt][reg], m2, 64);
                p2[mt][reg] += __shfl_xor(p2[mt][reg], m2, 64);
            }
    if (c == 0)
#pragma unroll
        for (int mt = 0; mt < 2; ++mt)
#pragma unroll
            for (int reg = 0; reg < 4; ++reg) {
                const int m = mt*16 + q*4 + reg;
                s_p1[m][w] = p1[mt][reg]; s_p2[m][w] = p2[mt][reg];
            }
    __syncthreads();
    if (t < 32) {
        const float S1 = s_p1[t][0]+s_p1[t][1]+s_p1[t][2]+s_p1[t][3];
        const float S2 = s_p2[t][0]+s_p2[t][1]+s_p2[t][2]+s_p2[t][3];
        const float mu = S1 * (1.f/(float)HH);
        const float var = S2 * (1.f/(float)HH) - mu*mu;
        s_mu[t] = mu; s_rstd[t] = rsqrtf(var + 1e-5f);
    }
    __syncthreads();

    float mu_r[2][4], rs_r[2][4], pa[2][4], pf[2][4];
#pragma unroll
    for (int mt = 0; mt < 2; ++mt)
#pragma unroll
        for (int reg = 0; reg < 4; ++reg) {
            const int m = mt*16 + q*4 + reg;
            mu_r[mt][reg] = s_mu[m]; rs_r[mt][reg] = s_rstd[m];
            pa[mt][reg] = 0.f; pf[mt][reg] = 0.f;
        }
#pragma unroll
    for (int mt = 0; mt < 2; ++mt)
#pragma unroll 4
        for (int nt = 0; nt < 16; ++nt) {
            const int j = w*256 + nt*16 + c;
            const float bb2 = b2[j], gg = ln_g[j], bbt = ln_b[j], fu = s_future[j];
#pragma unroll
            for (int reg = 0; reg < 4; ++reg) {
                const float d = accB[mt][nt][reg] + bb2;
                const float ar = (d - mu_r[mt][reg]) * rs_r[mt][reg] * gg + bbt;
                pa[mt][reg] += ar*ar; pf[mt][reg] += ar*fu;
            }
        }
#pragma unroll
    for (int m2 = 1; m2 <= 8; m2 <<= 1)
#pragma unroll
        for (int mt = 0; mt < 2; ++mt)
#pragma unroll
            for (int reg = 0; reg < 4; ++reg) {
                pa[mt][reg] += __shfl_xor(pa[mt][reg], m2, 64);
                pf[mt][reg] += __shfl_xor(pf[mt][reg], m2, 64);
            }
    if (c == 0)
#pragma unroll
        for (int mt = 0; mt < 2; ++mt)
#pragma unroll
            for (int reg = 0; reg < 4; ++reg) {
                const int m = mt*16 + q*4 + reg;
                s_pa[m][w] = pa[mt][reg]; s_pf[m][w] = pf[mt][reg];
            }
    __syncthreads();

    if (t < NA) {
        const float Sar2 = s_pa[t][0]+s_pa[t][1]+s_pa[t][2]+s_pa[t][3];
        const float Saf  = s_pf[t][0]+s_pf[t][1]+s_pf[t][2]+s_pf[t][3];
        const float anorm = fmaxf(sqrtf(Sar2), 1e-12f);
        const float sc = Saf / (anorm * fnorm);
        s_scores[t] = amask[r*NA + t] ? sc : -1e9f;
    }
    __syncthreads();

    if (t == 0) {
        const int validr = rvalid[r];
        float mx = -INFINITY;
#pragma unroll
        for (int a = 0; a < NA; ++a) mx = fmaxf(mx, s_scores[a]);
        float ex[NA]; float sesum = 0.f;
#pragma unroll
        for (int a = 0; a < NA; ++a) { ex[a] = __expf(s_scores[a] - mx); sesum += ex[a]; }
        float acc = 0.f; int denom = 0;
#pragma unroll
        for (int a = 0; a < NA; ++a) {
            const int mk = amask[r*NA + a];
            const int mv = (mk && validr) ? 1 : 0;
            const float rw = (ex[a] / sesum) * (float)mk;
            acc += rw * lp[r*NA + a] * (float)mv;
            denom += mv;
        }
        const float lossr = -acc / (float)(denom > 0 ? denom : 1) * (float)validr;
        const float normz = fmaxf((float)(*validcount), 1.f);
        atomicAdd(out, lossr / normz);
    }
}

// ---------------------------------------------------------------------------
extern "C" void kernel_launch(void* const* d_in, const int* in_sizes, int n_in,
                              void* d_out, int out_size, void* d_ws, size_t ws_size,
                              hipStream_t stream)
{
    const float* logits        = (const float*)d_in[0];
    const float* hidden        = (const float*)d_in[1];
    const int*   labels        = (const int*)d_in[2];
    const float* future        = (const float*)d_in[3];
    const unsigned char* fvld  = (const unsigned char*)d_in[4];
    const float* W1            = (const float*)d_in[5+1-1+1];  // see below
    // setup_inputs order: logits, hidden_states, labels, future_summaries,
    // future_valid, embed_weight, W1, b1, W2, b2, ln_g, ln_b
    const float* embed         = (const float*)d_in[5];
    const float* W1f           = (const float*)d_in[6];
    const float* b1            = (const float*)d_in[7];
    const float* W2f           = (const float*)d_in[8];
    const float* b2            = (const float*)d_in[9];
    const float* ln_g          = (const float*)d_in[10];
    const float* ln_b          = (const float*)d_in[11];
    (void)W1;
    float* out = (float*)d_out;

    // ws layout: W1T bf16 (8 MB) | W2T bf16 (4 MB) | counters | per-row arrays
    char* ws = (char*)d_ws;
    bf16* W1T = (bf16*)ws;                                    // 2048*2048*2
    bf16* W2T = (bf16*)(ws + (size_t)INNER*INNER*2);          // 1024*2048*2
    char* ws2 = ws + (size_t)INNER*INNER*2 + (size_t)HH*INNER*2;
    int*   validcount = (int*)ws2;
    int*   actions    = (int*)(ws2 + 16);
    int*   amask      = (int*)(ws2 + 16 + 1*BTOT*NA*4);
    float* lp         = (float*)(ws2 + 16 + 2*BTOT*NA*4);
    int*   rvalid     = (int*)(ws2 + 16 + 3*BTOT*NA*4);

    (void)hipMemsetAsync(d_out, 0, sizeof(float), stream);
    (void)hipMemsetAsync(ws2, 0, 16, stream);

    // W1: [2048][2048] -> W1T [n][k]; W2: [2048][1024] -> W2T [j][i]
    transpose_to_bf16<<<dim3(INNER/32, INNER/32), dim3(32, 8), 0, stream>>>(W1f, W1T, INNER, INNER);
    transpose_to_bf16<<<dim3(HH/32, INNER/32),   dim3(32, 8), 0, stream>>>(W2f, W2T, INNER, HH);

    topk_lse_kernel<<<BTOT, 256, 0, stream>>>(logits, labels, fvld,
                                              actions, amask, lp, rvalid, validcount);
    mlp_mfma_kernel<<<BTOT, 256, 0, stream>>>(hidden, future, embed, W1T, b1, W2T, b2,
                                              ln_g, ln_b, actions, amask, lp,
                                              rvalid, validcount, out);
}